// Round 1
// baseline (554.765 us; speedup 1.0000x reference)
//
#include <hip/hip_runtime.h>
#include <hip/hip_bf16.h>

#define S_LEN 1024
#define BATCH 2048
#define HID   64
#define MB    8               // batch rows per block
#define NBLK  (BATCH / MB)    // 256 blocks -> one per CU
#define NTHR  (MB * HID)      // 512 threads = 8 waves

typedef _Float16 half8 __attribute__((ext_vector_type(8)));
typedef float    f32x4 __attribute__((ext_vector_type(4)));

#define L2E 1.4426950408889634f
#define HSTRIDE 72            // h_lds row stride in halves (144 B, 16B-aligned rows)

__global__ __launch_bounds__(NTHR) void lstm_kernel(
    const float* __restrict__ x,      // (S, BATCH)
    const float* __restrict__ W_ih,   // (256,1)
    const float* __restrict__ W_hh,   // (256,64)
    const float* __restrict__ b_ih,   // (256,)
    const float* __restrict__ b_hh,   // (256,)
    const float* __restrict__ fc1_w,  // (128,64)
    const float* __restrict__ fc1_b,  // (128,)
    const float* __restrict__ fc2_w,  // (5,128)
    const float* __restrict__ fc2_b,  // (5,)
    float* __restrict__ out)          // (BATCH,5)
{
    // LDS: h (fp16, 16 rows x 72, rows 8..15 stay zero), gates (8x256 f32), fc1 buf
    __shared__ __align__(16) _Float16 h_lds[16 * HSTRIDE];     // 2304 B
    __shared__ __align__(16) float    gates_lds[MB * 256];     // 8 KB
    __shared__ __align__(16) float    head_lds[MB * 128];      // 4 KB

    const int tid  = threadIdx.x;
    const int lane = tid & 63;
    const int wave = tid >> 6;        // 0..7
    const int l15  = lane & 15;
    const int quad = lane >> 4;       // 0..3
    const int b0   = blockIdx.x * MB;

    // ---- init: zero h buffer (incl. pad rows 8..15, never written again) ----
    {
        unsigned* hz = (unsigned*)h_lds;
        for (int i = tid; i < (16 * HSTRIDE) / 2; i += NTHR) hz[i] = 0u;
    }

    // ---- stationary W_hh fragments (fp16, pre-scaled for exp2-based acts) ----
    // wave w owns N-tiles nt = 2w, 2w+1 (16 gate-columns each); K=64 -> 2 K-tiles.
    // B-frag layout (16x16x32 f16): lane holds B[k = quad*8+j][n = lane&15],
    // B[k][n] = W_hh[n][k]  (gates = h @ W_hh^T).
    half8 wfrag[2][2];
    for (int i = 0; i < 2; ++i) {
        const int nt = 2 * wave + i;
        const float s = (nt >= 8 && nt < 12) ? (-2.0f * L2E) : (-L2E); // g-rows vs i/f/o
        const int n = nt * 16 + l15;
        const float* wr = W_hh + n * HID + quad * 8;
        for (int kt = 0; kt < 2; ++kt) {
            half8 f;
            #pragma unroll
            for (int j = 0; j < 8; ++j) f[j] = (_Float16)(wr[kt * 32 + j] * s);
            wfrag[i][kt] = f;
        }
    }

    // ---- per-thread gate constants: thread owns pair (b = tid>>6, u = tid&63) ----
    const int ub = tid & 63;
    const int bb = tid >> 6;
    float wih_s[4], bias_s[4];
    #pragma unroll
    for (int g = 0; g < 4; ++g) {
        const int n = g * 64 + ub;
        const float s = (g == 2) ? (-2.0f * L2E) : (-L2E);
        wih_s[g]  = W_ih[n] * s;
        bias_s[g] = (b_ih[n] + b_hh[n]) * s;
    }

    const float* xcol = x + b0 + bb;       // x[s][b0+bb] at xcol[s*BATCH]
    float xcur = xcol[0];
    float c = 0.0f;

    __syncthreads();

    for (int s = 0; s < S_LEN; ++s) {
        // ---------- MFMA phase: gates = h @ W_hh^T (scaled) ----------
        // A-frag (16x16x32 f16): lane holds A[m = lane&15][k = quad*8+j]
        const _Float16* arow = h_lds + l15 * HSTRIDE + quad * 8;
        half8 a0 = *(const half8*)(arow);        // k-tile 0 (units 0..31)
        half8 a1 = *(const half8*)(arow + 32);   // k-tile 1 (units 32..63)
        #pragma unroll
        for (int i = 0; i < 2; ++i) {
            f32x4 acc = {0.f, 0.f, 0.f, 0.f};
            acc = __builtin_amdgcn_mfma_f32_16x16x32_f16(a0, wfrag[i][0], acc, 0, 0, 0);
            acc = __builtin_amdgcn_mfma_f32_16x16x32_f16(a1, wfrag[i][1], acc, 0, 0, 0);
            // C-layout: col = lane&15, row = quad*4 + reg. Rows >= 8 are pad.
            if (quad < 2) {
                const int ncol = (2 * wave + i) * 16 + l15;
                #pragma unroll
                for (int r = 0; r < 4; ++r)
                    gates_lds[(quad * 4 + r) * 256 + ncol] = acc[r];
            }
        }
        __syncthreads();

        // ---------- elementwise phase: one (b,u) pair per thread ----------
        float xn = 0.0f;
        if (s + 1 < S_LEN) xn = xcol[(size_t)(s + 1) * BATCH];  // prefetch

        const float* grow = gates_lds + bb * 256 + ub;
        const float gi = grow[0]   + xcur * wih_s[0] + bias_s[0];
        const float gf = grow[64]  + xcur * wih_s[1] + bias_s[1];
        const float gg = grow[128] + xcur * wih_s[2] + bias_s[2];
        const float go = grow[192] + xcur * wih_s[3] + bias_s[3];

        const float i_ = __builtin_amdgcn_rcpf(1.0f + __builtin_amdgcn_exp2f(gi));
        const float f_ = __builtin_amdgcn_rcpf(1.0f + __builtin_amdgcn_exp2f(gf));
        const float g_ = 2.0f * __builtin_amdgcn_rcpf(1.0f + __builtin_amdgcn_exp2f(gg)) - 1.0f;
        const float o_ = __builtin_amdgcn_rcpf(1.0f + __builtin_amdgcn_exp2f(go));

        c = f_ * c + i_ * g_;
        const float th = 2.0f * __builtin_amdgcn_rcpf(
                             1.0f + __builtin_amdgcn_exp2f((-2.0f * L2E) * c)) - 1.0f;
        const float h = o_ * th;

        h_lds[bb * HSTRIDE + ub] = (_Float16)h;
        xcur = xn;
        __syncthreads();
    }

    // ---------- fused FC head on final cell state c_n (no activation) ----------
    gates_lds[tid] = c;              // c buffer: [b][u] == tid
    __syncthreads();

    for (int idx = tid; idx < MB * 128; idx += NTHR) {
        const int b = idx >> 7, j = idx & 127;
        const float* wrow = fc1_w + j * HID;
        const float* crow = gates_lds + b * HID;
        float acc = fc1_b[j];
        #pragma unroll
        for (int k = 0; k < HID; k += 4)
            acc += crow[k] * wrow[k] + crow[k+1] * wrow[k+1]
                 + crow[k+2] * wrow[k+2] + crow[k+3] * wrow[k+3];
        head_lds[idx] = acc;
    }
    __syncthreads();

    if (tid < MB * 5) {
        const int b = tid / 5, q = tid % 5;
        const float* wrow = fc2_w + q * 128;
        const float* hrow = head_lds + b * 128;
        float acc = fc2_b[q];
        #pragma unroll 4
        for (int j = 0; j < 128; ++j) acc += hrow[j] * wrow[j];
        out[(b0 + b) * 5 + q] = acc;
    }
}

extern "C" void kernel_launch(void* const* d_in, const int* in_sizes, int n_in,
                              void* d_out, int out_size, void* d_ws, size_t ws_size,
                              hipStream_t stream) {
    const float* x     = (const float*)d_in[0];
    const float* W_ih  = (const float*)d_in[1];
    const float* W_hh  = (const float*)d_in[2];
    const float* b_ih  = (const float*)d_in[3];
    const float* b_hh  = (const float*)d_in[4];
    const float* fc1_w = (const float*)d_in[5];
    const float* fc1_b = (const float*)d_in[6];
    const float* fc2_w = (const float*)d_in[7];
    const float* fc2_b = (const float*)d_in[8];
    float* out = (float*)d_out;

    lstm_kernel<<<NBLK, NTHR, 0, stream>>>(x, W_ih, W_hh, b_ih, b_hh,
                                           fc1_w, fc1_b, fc2_w, fc2_b, out);
}